// Round 2
// baseline (499.821 us; speedup 1.0000x reference)
//
#include <hip/hip_runtime.h>

#define TT 32768          // tokens
#define HH 2048           // hidden
#define NE 64             // experts
#define TOPK 8

#define W_OFF 0
#define I_OFF (TT * TOPK)                 // 262144
#define P_OFF (2 * TT * TOPK)             // 524288
#define B_OFF (P_OFF + (size_t)TT * NE)   // 2621440

typedef __attribute__((ext_vector_type(8))) short short8;
typedef __attribute__((ext_vector_type(4))) float floatx4;

// Exact truncation split: f = h0 + h1 + h2 + eps, |eps| <~ 2^-22 |f|.
__device__ __forceinline__ void split3(const float4 v, ushort4& o0, ushort4& o1, ushort4& o2)
{
    const float* vf = (const float*)&v;
    ushort* p0 = (ushort*)&o0; ushort* p1 = (ushort*)&o1; ushort* p2 = (ushort*)&o2;
#pragma unroll
    for (int i = 0; i < 4; ++i) {
        float f = vf[i];
        unsigned u0 = __float_as_uint(f);
        float h0 = __uint_as_float(u0 & 0xffff0000u);
        float r1 = f - h0;
        unsigned u1 = __float_as_uint(r1);
        float h1 = __uint_as_float(u1 & 0xffff0000u);
        float r2 = r1 - h1;
        unsigned u2 = __float_as_uint(r2);
        p0[i] = (ushort)(u0 >> 16);
        p1[i] = (ushort)(u1 >> 16);
        p2[i] = (ushort)(u2 >> 16);
    }
}

// ---------------------------------------------------------------------------
// One-time prep: gw (64x2048 f32) -> 3 bf16 split planes in MFMA-fragment
// order. Layout (shorts): [((i*4 + nt)*3 + p)*512 + lane*8 + h] where
// i = kchunk*2 + s, e = nt*16 + (lane&15), g = s*4 + (lane>>4),
// content = plane_p(gw[e][i*32 + (lane>>4)*8 + h]).  768 KB total.
// ---------------------------------------------------------------------------
__global__ void prep_b(const float* __restrict__ gw, ushort* __restrict__ bp)
{
    const int n = blockIdx.x * 256 + threadIdx.x;   // 0..16383 = (e, granule)
    const int e = n >> 8;
    const int gr = n & 255;                          // k0 = gr*8
    const int c = gr >> 3, g = gr & 7;
    const int s = g >> 2, lqq = g & 3;
    const int nt = e >> 4, lrr = e & 15;
    const int lane = lqq * 16 + lrr;
    const float4 v0 = *(const float4*)&gw[(size_t)e * HH + gr * 8];
    const float4 v1 = *(const float4*)&gw[(size_t)e * HH + gr * 8 + 4];
    ushort4 p0l, p1l, p2l, p0h, p1h, p2h;
    split3(v0, p0l, p1l, p2l);
    split3(v1, p0h, p1h, p2h);
    const int i = c * 2 + s;
    ushort* base = bp + (size_t)((i * 4 + nt) * 3) * 512 + lane * 8;
    *(ushort4*)(base + 0 * 512)     = p0l;
    *(ushort4*)(base + 0 * 512 + 4) = p0h;
    *(ushort4*)(base + 1 * 512)     = p1l;
    *(ushort4*)(base + 1 * 512 + 4) = p1h;
    *(ushort4*)(base + 2 * 512)     = p2l;
    *(ushort4*)(base + 2 * 512 + 4) = p2h;
}

// ---------------------------------------------------------------------------
// Barrier-free GEMM: 4 waves/block, wave = 16 tokens x 64 experts.
// 512 blocks -> 2 blocks/CU. No LDS. Each lane loads its own A granule
// (8 floats of row t), split3 in registers -> A fragments; B fragments come
// pre-split/pre-swizzled from bp (L1/L2-resident), 1 KB coalesced per read.
// Same fragment contents + per-accumulator MFMA order as the verified
// kernel -> logits bitwise identical.
// ---------------------------------------------------------------------------
__global__ __launch_bounds__(256, 2) void gate_gemm(
    const float* __restrict__ x, const ushort* __restrict__ bp,
    float* __restrict__ logits)
{
    const int tid = threadIdx.x;
    const int lane = tid & 63;
    const int wv = tid >> 6;            // 0..3
    const int lr = lane & 15;
    const int lq = lane >> 4;
    const int t = blockIdx.x * 64 + wv * 16 + lr;   // this lane's A row

    const float* xrow = x + (size_t)t * HH + lq * 8;

    floatx4 accB[4], accS[4];
#pragma unroll
    for (int nt = 0; nt < 4; ++nt) { accB[nt] = (floatx4)0.f; accS[nt] = (floatx4)0.f; }

    // distance-2 prefetch, hand-peeled parity (all reg indices static)
    float4 pa0l = *(const float4*)(xrow + 0);
    float4 pa0h = *(const float4*)(xrow + 4);
    float4 pa1l = *(const float4*)(xrow + 32);
    float4 pa1h = *(const float4*)(xrow + 36);

    union U8 { short8 s8; ushort4 u4[2]; };

    for (int i = 0; i < 64; i += 2) {
        // ---- step i (even): consume pa0, prefetch i+2 ----
        {
            ushort4 q0l, q1l, q2l, q0h, q1h, q2h;
            split3(pa0l, q0l, q1l, q2l);
            split3(pa0h, q0h, q1h, q2h);
            const int ip = (i + 2) & 63;            // wraps harmlessly at tail
            pa0l = *(const float4*)(xrow + ip * 32);
            pa0h = *(const float4*)(xrow + ip * 32 + 4);
            U8 a0, a1, a2;
            a0.u4[0] = q0l; a0.u4[1] = q0h;
            a1.u4[0] = q1l; a1.u4[1] = q1h;
            a2.u4[0] = q2l; a2.u4[1] = q2h;
            const ushort* bpi = bp + (size_t)i * 6144 + lane * 8;
#pragma unroll
            for (int nt = 0; nt < 4; ++nt) {
                const short8 b0 = *(const short8*)(bpi + (nt * 3 + 0) * 512);
                const short8 b1 = *(const short8*)(bpi + (nt * 3 + 1) * 512);
                const short8 b2 = *(const short8*)(bpi + (nt * 3 + 2) * 512);
                accB[nt] = __builtin_amdgcn_mfma_f32_16x16x32_bf16(a0.s8, b0, accB[nt], 0, 0, 0);
                accS[nt] = __builtin_amdgcn_mfma_f32_16x16x32_bf16(a0.s8, b1, accS[nt], 0, 0, 0);
                accS[nt] = __builtin_amdgcn_mfma_f32_16x16x32_bf16(a1.s8, b0, accS[nt], 0, 0, 0);
                accS[nt] = __builtin_amdgcn_mfma_f32_16x16x32_bf16(a0.s8, b2, accS[nt], 0, 0, 0);
                accS[nt] = __builtin_amdgcn_mfma_f32_16x16x32_bf16(a1.s8, b1, accS[nt], 0, 0, 0);
                accS[nt] = __builtin_amdgcn_mfma_f32_16x16x32_bf16(a2.s8, b0, accS[nt], 0, 0, 0);
            }
        }
        // ---- step i+1 (odd): consume pa1, prefetch i+3 ----
        {
            ushort4 q0l, q1l, q2l, q0h, q1h, q2h;
            split3(pa1l, q0l, q1l, q2l);
            split3(pa1h, q0h, q1h, q2h);
            const int ip = (i + 3) & 63;
            pa1l = *(const float4*)(xrow + ip * 32);
            pa1h = *(const float4*)(xrow + ip * 32 + 4);
            U8 a0, a1, a2;
            a0.u4[0] = q0l; a0.u4[1] = q0h;
            a1.u4[0] = q1l; a1.u4[1] = q1h;
            a2.u4[0] = q2l; a2.u4[1] = q2h;
            const ushort* bpi = bp + (size_t)(i + 1) * 6144 + lane * 8;
#pragma unroll
            for (int nt = 0; nt < 4; ++nt) {
                const short8 b0 = *(const short8*)(bpi + (nt * 3 + 0) * 512);
                const short8 b1 = *(const short8*)(bpi + (nt * 3 + 1) * 512);
                const short8 b2 = *(const short8*)(bpi + (nt * 3 + 2) * 512);
                accB[nt] = __builtin_amdgcn_mfma_f32_16x16x32_bf16(a0.s8, b0, accB[nt], 0, 0, 0);
                accS[nt] = __builtin_amdgcn_mfma_f32_16x16x32_bf16(a0.s8, b1, accS[nt], 0, 0, 0);
                accS[nt] = __builtin_amdgcn_mfma_f32_16x16x32_bf16(a1.s8, b0, accS[nt], 0, 0, 0);
                accS[nt] = __builtin_amdgcn_mfma_f32_16x16x32_bf16(a0.s8, b2, accS[nt], 0, 0, 0);
                accS[nt] = __builtin_amdgcn_mfma_f32_16x16x32_bf16(a1.s8, b1, accS[nt], 0, 0, 0);
                accS[nt] = __builtin_amdgcn_mfma_f32_16x16x32_bf16(a2.s8, b0, accS[nt], 0, 0, 0);
            }
        }
    }

    // C/D layout (verified m89/m91): col = lane&15 (expert), row = quad*4+reg
    const int tokw = blockIdx.x * 64 + wv * 16 + lq * 4;
#pragma unroll
    for (int nt = 0; nt < 4; ++nt)
#pragma unroll
        for (int rg = 0; rg < 4; ++rg)
            logits[(size_t)(tokw + rg) * NE + nt * 16 + lr] = accB[nt][rg] + accS[nt][rg];
}

// ---------------------------------------------------------------------------
// Epilogue: one token per THREAD, 64-expert row fully in registers.
// (verified round-1; unchanged)
// ---------------------------------------------------------------------------
__global__ __launch_bounds__(64) void epilogue_k(
    const float* __restrict__ eb, const float* __restrict__ noise,
    float* __restrict__ out, int* __restrict__ counts)
{
    __shared__ float s_eb[NE];
    __shared__ int lc[NE];
    const int tid = threadIdx.x;                 // 0..63
    const int t = blockIdx.x * 64 + tid;         // token
    s_eb[tid] = eb[tid];
    lc[tid] = 0;
    __syncthreads();

    float* probs = out + P_OFF;
    const float4* lrow = (const float4*)&probs[(size_t)t * NE];
    const float4* nrow = (const float4*)&noise[(size_t)t * NE];

    float v[NE];
#pragma unroll
    for (int j = 0; j < 16; ++j) {
        float4 lg = lrow[j];
        float4 nz = nrow[j];
        v[4 * j + 0] = lg.x + nz.x * 0.01f + s_eb[4 * j + 0];
        v[4 * j + 1] = lg.y + nz.y * 0.01f + s_eb[4 * j + 1];
        v[4 * j + 2] = lg.z + nz.z * 0.01f + s_eb[4 * j + 2];
        v[4 * j + 3] = lg.w + nz.w * 0.01f + s_eb[4 * j + 3];
    }

    float m = v[0];
#pragma unroll
    for (int i = 1; i < NE; ++i) m = fmaxf(m, v[i]);

#pragma unroll
    for (int i = 0; i < NE; ++i) v[i] = expf(v[i] - m);

    float tr[32];
#pragma unroll
    for (int i = 0; i < 32; ++i) tr[i] = v[2 * i] + v[2 * i + 1];
#pragma unroll
    for (int i = 0; i < 16; ++i) tr[i] = tr[2 * i] + tr[2 * i + 1];
#pragma unroll
    for (int i = 0; i < 8; ++i) tr[i] = tr[2 * i] + tr[2 * i + 1];
#pragma unroll
    for (int i = 0; i < 4; ++i) tr[i] = tr[2 * i] + tr[2 * i + 1];
#pragma unroll
    for (int i = 0; i < 2; ++i) tr[i] = tr[2 * i] + tr[2 * i + 1];
    const float inv = 1.f / (tr[0] + tr[1]);

#pragma unroll
    for (int i = 0; i < NE; ++i) v[i] = v[i] * inv;

    float4* prow = (float4*)&probs[(size_t)t * NE];
#pragma unroll
    for (int j = 0; j < 16; ++j)
        prow[j] = make_float4(v[4 * j + 0], v[4 * j + 1], v[4 * j + 2], v[4 * j + 3]);

    float wq[TOPK];
    int iq[TOPK];
    float wsum = 0.f;
#pragma unroll
    for (int r = 0; r < TOPK; ++r) {
        float bv = v[0]; int bi = 0;
#pragma unroll
        for (int i = 1; i < NE; ++i)
            if (v[i] > bv) { bv = v[i]; bi = i; }
        wsum += bv;
        wq[r] = bv;
        iq[r] = bi;
#pragma unroll
        for (int i = 0; i < NE; ++i)
            if (i == bi) v[i] = -1.f;
    }
    const float winv = 1.f / wsum;

    float4* wrow = (float4*)&out[W_OFF + (size_t)t * TOPK];
    wrow[0] = make_float4(wq[0] * winv, wq[1] * winv, wq[2] * winv, wq[3] * winv);
    wrow[1] = make_float4(wq[4] * winv, wq[5] * winv, wq[6] * winv, wq[7] * winv);
    float4* irow = (float4*)&out[I_OFF + (size_t)t * TOPK];
    irow[0] = make_float4((float)iq[0], (float)iq[1], (float)iq[2], (float)iq[3]);
    irow[1] = make_float4((float)iq[4], (float)iq[5], (float)iq[6], (float)iq[7]);

#pragma unroll
    for (int r = 0; r < TOPK; ++r) atomicAdd(&lc[iq[r]], 1);
    __syncthreads();
    if (lc[tid]) atomicAdd(&counts[tid], lc[tid]);
}

__global__ void zero_counts_k(int* c)
{
    if (threadIdx.x < NE) c[threadIdx.x] = 0;
}

// sign(load - 1/64) computed exactly: counts/2^18 is exact in fp32
__global__ void bias_k(const int* __restrict__ c, const float* __restrict__ eb,
                       float* __restrict__ out)
{
    int e = threadIdx.x;
    if (e < NE) {
        float load = (float)c[e] * (1.0f / 262144.0f);
        float err = load - 0.015625f;
        float sg = (err > 0.f) ? 1.f : ((err < 0.f) ? -1.f : 0.f);
        out[B_OFF + e] = eb[e] - 0.001f * sg;
    }
}

extern "C" void kernel_launch(void* const* d_in, const int* in_sizes, int n_in,
                              void* d_out, int out_size, void* d_ws, size_t ws_size,
                              hipStream_t stream)
{
    const float* x     = (const float*)d_in[0];
    const float* gw    = (const float*)d_in[1];
    const float* eb    = (const float*)d_in[2];
    const float* noise = (const float*)d_in[3];
    float* out = (float*)d_out;
    int* counts = (int*)d_ws;
    ushort* bp = (ushort*)((char*)d_ws + 4096);   // 768 KB prepped B planes

    hipLaunchKernelGGL(zero_counts_k, dim3(1), dim3(64), 0, stream, counts);
    hipLaunchKernelGGL(prep_b, dim3(64), dim3(256), 0, stream, gw, bp);
    hipLaunchKernelGGL(gate_gemm, dim3(TT / 64), dim3(256), 0, stream,
                       x, bp, out + P_OFF);
    hipLaunchKernelGGL(epilogue_k, dim3(TT / 64), dim3(64), 0, stream,
                       eb, noise, out, counts);
    hipLaunchKernelGGL(bias_k, dim3(1), dim3(64), 0, stream, counts, eb, out);
}

// Round 3
// 418.987 us; speedup vs baseline: 1.1929x; 1.1929x over previous
//
#include <hip/hip_runtime.h>

#define TT 32768          // tokens
#define HH 2048           // hidden
#define NE 64             // experts
#define TOPK 8

#define W_OFF 0
#define I_OFF (TT * TOPK)                 // 262144
#define P_OFF (2 * TT * TOPK)             // 524288
#define B_OFF (P_OFF + (size_t)TT * NE)   // 2621440

typedef __attribute__((ext_vector_type(8))) short short8;
typedef __attribute__((ext_vector_type(4))) float floatx4;

// Exact truncation split: f = h0 + h1 + h2 + eps, |eps| <~ 2^-22 |f|.
__device__ __forceinline__ void split3(const float4 v, ushort4& o0, ushort4& o1, ushort4& o2)
{
    const float* vf = (const float*)&v;
    ushort* p0 = (ushort*)&o0; ushort* p1 = (ushort*)&o1; ushort* p2 = (ushort*)&o2;
#pragma unroll
    for (int i = 0; i < 4; ++i) {
        float f = vf[i];
        unsigned u0 = __float_as_uint(f);
        float h0 = __uint_as_float(u0 & 0xffff0000u);
        float r1 = f - h0;
        unsigned u1 = __float_as_uint(r1);
        float h1 = __uint_as_float(u1 & 0xffff0000u);
        float r2 = r1 - h1;
        unsigned u2 = __float_as_uint(r2);
        p0[i] = (ushort)(u0 >> 16);
        p1[i] = (ushort)(u1 >> 16);
        p2[i] = (ushort)(u2 >> 16);
    }
}

// ---------------------------------------------------------------------------
// One-time prep: gw (64x2048 f32) -> 3 bf16 split planes in MFMA-fragment
// order. Layout (shorts): [((i*4 + nt)*3 + p)*512 + lane*8 + h] where
// i = kchunk*2 + s, e = nt*16 + (lane&15), g = s*4 + (lane>>4),
// content = plane_p(gw[e][i*32 + (lane>>4)*8 + h]).  768 KB total.
// Step i occupies the contiguous 12288-byte range [i*12288, (i+1)*12288).
// ---------------------------------------------------------------------------
__global__ void prep_b(const float* __restrict__ gw, ushort* __restrict__ bp)
{
    const int n = blockIdx.x * 256 + threadIdx.x;   // 0..16383 = (e, granule)
    const int e = n >> 8;
    const int gr = n & 255;                          // k0 = gr*8
    const int c = gr >> 3, g = gr & 7;
    const int s = g >> 2, lqq = g & 3;
    const int nt = e >> 4, lrr = e & 15;
    const int lane = lqq * 16 + lrr;
    const float4 v0 = *(const float4*)&gw[(size_t)e * HH + gr * 8];
    const float4 v1 = *(const float4*)&gw[(size_t)e * HH + gr * 8 + 4];
    ushort4 p0l, p1l, p2l, p0h, p1h, p2h;
    split3(v0, p0l, p1l, p2l);
    split3(v1, p0h, p1h, p2h);
    const int i = c * 2 + s;
    ushort* base = bp + (size_t)((i * 4 + nt) * 3) * 512 + lane * 8;
    *(ushort4*)(base + 0 * 512)     = p0l;
    *(ushort4*)(base + 0 * 512 + 4) = p0h;
    *(ushort4*)(base + 1 * 512)     = p1l;
    *(ushort4*)(base + 1 * 512 + 4) = p1h;
    *(ushort4*)(base + 2 * 512)     = p2l;
    *(ushort4*)(base + 2 * 512 + 4) = p2h;
}

__device__ __forceinline__ void load_lds16(const void* g, void* l)
{
    __builtin_amdgcn_global_load_lds(
        (const __attribute__((address_space(1))) unsigned int*)g,
        (__attribute__((address_space(3))) unsigned int*)l, 16, 0, 0);
}

// ---------------------------------------------------------------------------
// gate_gemm: 4 waves/block, wave = 16 tokens x 64 experts; block = 64 tokens.
// A: per-lane register path (each x element loaded+split exactly once).
// B: prepped planes staged block-wide into LDS via global_load_lds,
//    triple-buffered, stage-ahead-1, stage issued BEFORE the MFMA block so
//    its L2/L3 latency hides under compute. One barrier per K-step.
// Per-CU LDS-read 6.1 MB (~30us) < x HBM floor (~42us) -> x-bound by design.
// Fragment bytes + MFMA order identical to verified kernel -> logits bitwise.
// ---------------------------------------------------------------------------
__global__ __launch_bounds__(256, 2) void gate_gemm(
    const float* __restrict__ x, const ushort* __restrict__ bp,
    float* __restrict__ logits)
{
    __shared__ ushort bbuf[3][6144];    // 3 x 12 KB B-plane buffers

    const int tid = threadIdx.x;
    const int lane = tid & 63;
    const int wv = tid >> 6;            // 0..3
    const int lr = lane & 15;
    const int lq = lane >> 4;
    const int t = blockIdx.x * 64 + wv * 16 + lr;   // this lane's A row

    const float* xrow = x + (size_t)t * HH + lq * 8;

    floatx4 accB[4], accS[4];
#pragma unroll
    for (int nt = 0; nt < 4; ++nt) { accB[nt] = (floatx4)0.f; accS[nt] = (floatx4)0.f; }

    // prologue: stage step 0, load x for steps 0 and 1
    {
        const ushort* g = bp + tid * 8;
#pragma unroll
        for (int r = 0; r < 3; ++r)
            load_lds16(g + r * 2048, &bbuf[0][r * 2048 + tid * 8]);
    }
    float4 pe_l = *(const float4*)(xrow + 0);
    float4 pe_h = *(const float4*)(xrow + 4);
    float4 po_l = *(const float4*)(xrow + 32);
    float4 po_h = *(const float4*)(xrow + 36);

    union U8 { short8 s8; ushort4 u4[2]; };

    __syncthreads();                    // buf0 staged & visible

    for (int i = 0; i < 64; i += 2) {
        // ---------------- even step i ----------------
        {
            const int bcur = i % 3, bnxt = (i + 1) % 3;
            // stage step i+1 early (i+1 <= 63 always here)
            {
                const ushort* g = bp + (size_t)(i + 1) * 6144 + tid * 8;
#pragma unroll
                for (int r = 0; r < 3; ++r)
                    load_lds16(g + r * 2048, &bbuf[bnxt][r * 2048 + tid * 8]);
            }
            ushort4 q0l, q1l, q2l, q0h, q1h, q2h;
            split3(pe_l, q0l, q1l, q2l);
            split3(pe_h, q0h, q1h, q2h);
            {
                const int ip = (i + 2) & 63;
                pe_l = *(const float4*)(xrow + ip * 32);
                pe_h = *(const float4*)(xrow + ip * 32 + 4);
            }
            U8 a0, a1, a2;
            a0.u4[0] = q0l; a0.u4[1] = q0h;
            a1.u4[0] = q1l; a1.u4[1] = q1h;
            a2.u4[0] = q2l; a2.u4[1] = q2h;
            const ushort* bb = &bbuf[bcur][lane * 8];
#pragma unroll
            for (int nt = 0; nt < 4; ++nt) {
                const short8 b0 = *(const short8*)(bb + (nt * 3 + 0) * 512);
                const short8 b1 = *(const short8*)(bb + (nt * 3 + 1) * 512);
                const short8 b2 = *(const short8*)(bb + (nt * 3 + 2) * 512);
                accB[nt] = __builtin_amdgcn_mfma_f32_16x16x32_bf16(a0.s8, b0, accB[nt], 0, 0, 0);
                accS[nt] = __builtin_amdgcn_mfma_f32_16x16x32_bf16(a0.s8, b1, accS[nt], 0, 0, 0);
                accS[nt] = __builtin_amdgcn_mfma_f32_16x16x32_bf16(a1.s8, b0, accS[nt], 0, 0, 0);
                accS[nt] = __builtin_amdgcn_mfma_f32_16x16x32_bf16(a0.s8, b2, accS[nt], 0, 0, 0);
                accS[nt] = __builtin_amdgcn_mfma_f32_16x16x32_bf16(a1.s8, b1, accS[nt], 0, 0, 0);
                accS[nt] = __builtin_amdgcn_mfma_f32_16x16x32_bf16(a2.s8, b0, accS[nt], 0, 0, 0);
            }
            __syncthreads();            // drains stage(i+1); buf ready next step
        }
        // ---------------- odd step i+1 ----------------
        {
            const int bcur = (i + 1) % 3, bnxt = (i + 2) % 3;
            if (i + 2 < 64) {
                const ushort* g = bp + (size_t)(i + 2) * 6144 + tid * 8;
#pragma unroll
                for (int r = 0; r < 3; ++r)
                    load_lds16(g + r * 2048, &bbuf[bnxt][r * 2048 + tid * 8]);
            }
            ushort4 q0l, q1l, q2l, q0h, q1h, q2h;
            split3(po_l, q0l, q1l, q2l);
            split3(po_h, q0h, q1h, q2h);
            {
                const int ip = (i + 3) & 63;
                po_l = *(const float4*)(xrow + ip * 32);
                po_h = *(const float4*)(xrow + ip * 32 + 4);
            }
            U8 a0, a1, a2;
            a0.u4[0] = q0l; a0.u4[1] = q0h;
            a1.u4[0] = q1l; a1.u4[1] = q1h;
            a2.u4[0] = q2l; a2.u4[1] = q2h;
            const ushort* bb = &bbuf[bcur][lane * 8];
#pragma unroll
            for (int nt = 0; nt < 4; ++nt) {
                const short8 b0 = *(const short8*)(bb + (nt * 3 + 0) * 512);
                const short8 b1 = *(const short8*)(bb + (nt * 3 + 1) * 512);
                const short8 b2 = *(const short8*)(bb + (nt * 3 + 2) * 512);
                accB[nt] = __builtin_amdgcn_mfma_f32_16x16x32_bf16(a0.s8, b0, accB[nt], 0, 0, 0);
                accS[nt] = __builtin_amdgcn_mfma_f32_16x16x32_bf16(a0.s8, b1, accS[nt], 0, 0, 0);
                accS[nt] = __builtin_amdgcn_mfma_f32_16x16x32_bf16(a1.s8, b0, accS[nt], 0, 0, 0);
                accS[nt] = __builtin_amdgcn_mfma_f32_16x16x32_bf16(a0.s8, b2, accS[nt], 0, 0, 0);
                accS[nt] = __builtin_amdgcn_mfma_f32_16x16x32_bf16(a1.s8, b1, accS[nt], 0, 0, 0);
                accS[nt] = __builtin_amdgcn_mfma_f32_16x16x32_bf16(a2.s8, b0, accS[nt], 0, 0, 0);
            }
            __syncthreads();
        }
    }

    // C/D layout (verified m89/m91): col = lane&15 (expert), row = quad*4+reg
    const int tokw = blockIdx.x * 64 + wv * 16 + lq * 4;
#pragma unroll
    for (int nt = 0; nt < 4; ++nt)
#pragma unroll
        for (int rg = 0; rg < 4; ++rg)
            logits[(size_t)(tokw + rg) * NE + nt * 16 + lr] = accB[nt][rg] + accS[nt][rg];
}

// ---------------------------------------------------------------------------
// Epilogue: one token per THREAD, 64-expert row fully in registers.
// (verified round-1; unchanged)
// ---------------------------------------------------------------------------
__global__ __launch_bounds__(64) void epilogue_k(
    const float* __restrict__ eb, const float* __restrict__ noise,
    float* __restrict__ out, int* __restrict__ counts)
{
    __shared__ float s_eb[NE];
    __shared__ int lc[NE];
    const int tid = threadIdx.x;                 // 0..63
    const int t = blockIdx.x * 64 + tid;         // token
    s_eb[tid] = eb[tid];
    lc[tid] = 0;
    __syncthreads();

    float* probs = out + P_OFF;
    const float4* lrow = (const float4*)&probs[(size_t)t * NE];
    const float4* nrow = (const float4*)&noise[(size_t)t * NE];

    float v[NE];
#pragma unroll
    for (int j = 0; j < 16; ++j) {
        float4 lg = lrow[j];
        float4 nz = nrow[j];
        v[4 * j + 0] = lg.x + nz.x * 0.01f + s_eb[4 * j + 0];
        v[4 * j + 1] = lg.y + nz.y * 0.01f + s_eb[4 * j + 1];
        v[4 * j + 2] = lg.z + nz.z * 0.01f + s_eb[4 * j + 2];
        v[4 * j + 3] = lg.w + nz.w * 0.01f + s_eb[4 * j + 3];
    }

    float m = v[0];
#pragma unroll
    for (int i = 1; i < NE; ++i) m = fmaxf(m, v[i]);

#pragma unroll
    for (int i = 0; i < NE; ++i) v[i] = expf(v[i] - m);

    float tr[32];
#pragma unroll
    for (int i = 0; i < 32; ++i) tr[i] = v[2 * i] + v[2 * i + 1];
#pragma unroll
    for (int i = 0; i < 16; ++i) tr[i] = tr[2 * i] + tr[2 * i + 1];
#pragma unroll
    for (int i = 0; i < 8; ++i) tr[i] = tr[2 * i] + tr[2 * i + 1];
#pragma unroll
    for (int i = 0; i < 4; ++i) tr[i] = tr[2 * i] + tr[2 * i + 1];
#pragma unroll
    for (int i = 0; i < 2; ++i) tr[i] = tr[2 * i] + tr[2 * i + 1];
    const float inv = 1.f / (tr[0] + tr[1]);

#pragma unroll
    for (int i = 0; i < NE; ++i) v[i] = v[i] * inv;

    float4* prow = (float4*)&probs[(size_t)t * NE];
#pragma unroll
    for (int j = 0; j < 16; ++j)
        prow[j] = make_float4(v[4 * j + 0], v[4 * j + 1], v[4 * j + 2], v[4 * j + 3]);

    float wq[TOPK];
    int iq[TOPK];
    float wsum = 0.f;
#pragma unroll
    for (int r = 0; r < TOPK; ++r) {
        float bv = v[0]; int bi = 0;
#pragma unroll
        for (int i = 1; i < NE; ++i)
            if (v[i] > bv) { bv = v[i]; bi = i; }
        wsum += bv;
        wq[r] = bv;
        iq[r] = bi;
#pragma unroll
        for (int i = 0; i < NE; ++i)
            if (i == bi) v[i] = -1.f;
    }
    const float winv = 1.f / wsum;

    float4* wrow = (float4*)&out[W_OFF + (size_t)t * TOPK];
    wrow[0] = make_float4(wq[0] * winv, wq[1] * winv, wq[2] * winv, wq[3] * winv);
    wrow[1] = make_float4(wq[4] * winv, wq[5] * winv, wq[6] * winv, wq[7] * winv);
    float4* irow = (float4*)&out[I_OFF + (size_t)t * TOPK];
    irow[0] = make_float4((float)iq[0], (float)iq[1], (float)iq[2], (float)iq[3]);
    irow[1] = make_float4((float)iq[4], (float)iq[5], (float)iq[6], (float)iq[7]);

#pragma unroll
    for (int r = 0; r < TOPK; ++r) atomicAdd(&lc[iq[r]], 1);
    __syncthreads();
    if (lc[tid]) atomicAdd(&counts[tid], lc[tid]);
}

__global__ void zero_counts_k(int* c)
{
    if (threadIdx.x < NE) c[threadIdx.x] = 0;
}

// sign(load - 1/64) computed exactly: counts/2^18 is exact in fp32
__global__ void bias_k(const int* __restrict__ c, const float* __restrict__ eb,
                       float* __restrict__ out)
{
    int e = threadIdx.x;
    if (e < NE) {
        float load = (float)c[e] * (1.0f / 262144.0f);
        float err = load - 0.015625f;
        float sg = (err > 0.f) ? 1.f : ((err < 0.f) ? -1.f : 0.f);
        out[B_OFF + e] = eb[e] - 0.001f * sg;
    }
}

extern "C" void kernel_launch(void* const* d_in, const int* in_sizes, int n_in,
                              void* d_out, int out_size, void* d_ws, size_t ws_size,
                              hipStream_t stream)
{
    const float* x     = (const float*)d_in[0];
    const float* gw    = (const float*)d_in[1];
    const float* eb    = (const float*)d_in[2];
    const float* noise = (const float*)d_in[3];
    float* out = (float*)d_out;
    int* counts = (int*)d_ws;
    ushort* bp = (ushort*)((char*)d_ws + 4096);   // 768 KB prepped B planes

    hipLaunchKernelGGL(zero_counts_k, dim3(1), dim3(64), 0, stream, counts);
    hipLaunchKernelGGL(prep_b, dim3(64), dim3(256), 0, stream, gw, bp);
    hipLaunchKernelGGL(gate_gemm, dim3(TT / 64), dim3(256), 0, stream,
                       x, bp, out + P_OFF);
    hipLaunchKernelGGL(epilogue_k, dim3(TT / 64), dim3(64), 0, stream,
                       eb, noise, out, counts);
    hipLaunchKernelGGL(bias_k, dim3(1), dim3(64), 0, stream, counts, eb, out);
}